// Round 8
// baseline (198.721 us; speedup 1.0000x reference)
//
#include <hip/hip_runtime.h>
#include <hip/hip_bf16.h>
#include <cmath>
#include <stdint.h>

// ---------------- problem constants ----------------
#define K_DIM 1024
#define NH    16
#define HD    64
#define T     2048
#define NTOK  4096   // b*t = 2*2048
#define NBH   32     // b*h

typedef __bf16 bf16x8 __attribute__((ext_vector_type(8)));
typedef float  f32x4  __attribute__((ext_vector_type(4)));

__device__ __forceinline__ unsigned short f2bf(float f) {
  union { float f; unsigned u; } v; v.f = f;
  unsigned u = v.u;
  return (unsigned short)((u + 0x7FFFu + ((u >> 16) & 1u)) >> 16);
}
// packed round-nearest-even via v_cvt_pk_bf16_f32
__device__ __forceinline__ ushort4 pk4(float a, float b, float c, float d) {
  union { __hip_bfloat162 h[2]; ushort4 u; } r;
  r.h[0] = __float22bfloat162_rn(float2{a, b});
  r.h[1] = __float22bfloat162_rn(float2{c, d});
  return r.u;
}

__device__ __forceinline__ void gload16(const void* g, void* l) {
  __builtin_amdgcn_global_load_lds(
      (__attribute__((address_space(1))) void*)(g),
      (__attribute__((address_space(3))) void*)(l),
      16, 0, 0);
}

// ---------------- fp32 -> bf16 conversion ----------------
// Wq is pre-scaled by 0.125*log2(e) so attn can exp2() scores directly.
__global__ void convert_kernel(const float* __restrict__ x,
                               const float* __restrict__ Wq,
                               const float* __restrict__ Wk,
                               const float* __restrict__ Wv,
                               const float* __restrict__ Wo,
                               unsigned short* __restrict__ xb,
                               unsigned short* __restrict__ wqkv,
                               unsigned short* __restrict__ wob)
{
  const size_t NX = (size_t)NTOK * K_DIM;   // 4M
  const size_t NW = (size_t)K_DIM * K_DIM;  // 1M
  size_t i = ((size_t)blockIdx.x * blockDim.x + threadIdx.x) * 4;
  const float* src; unsigned short* dst; size_t off;
  float scale = 1.f;
  if (i < NX)             { src = x;  dst = xb;          off = i; }
  else if (i < NX + NW)   { src = Wq; dst = wqkv;        off = i - NX;
                            scale = 0.18033688011112042f; }
  else if (i < NX + 2*NW) { src = Wk; dst = wqkv + NW;   off = i - NX - NW; }
  else if (i < NX + 3*NW) { src = Wv; dst = wqkv + 2*NW; off = i - NX - 2*NW; }
  else                    { src = Wo; dst = wob;         off = i - NX - 3*NW; }
  float4 v = *(const float4*)(src + off);
  *(ushort4*)(dst + off) = pk4(v.x * scale, v.y * scale, v.z * scale, v.w * scale);
}

// ---------------- B^T GEMM: C[m][n] = sum_k A[m*1024+k] * B[n*1024+k] ----------------
// TMxTN tile, BK=64, 256 threads (2x2 waves). XOR-swizzled LDS (chunk ^= row&7).
// MODE 1 (fused QKV): A=[Wq;Wk;Wv], m=chan in [0,3072), n=token.
//   q/k: packed ushort4 along d; v: b16 scatter to vt[bh][d][t] (t-coalesced).
// MODE 2 (out-proj):  A=Wo, m=chan in [0,1024), n=token -> out[t][chan]+bias, float4.
template <int MODE, int TM, int TN>
__global__ __launch_bounds__(256, 2)
void gemm_bt(const unsigned short* __restrict__ A,
             const unsigned short* __restrict__ B,
             unsigned short* __restrict__ o_q,
             unsigned short* __restrict__ o_k,
             unsigned short* __restrict__ o_v,
             float* __restrict__ o_f,
             const float* __restrict__ bias)
{
  __shared__ unsigned short Asm[TM * 64];
  __shared__ unsigned short Bsm[TN * 64];
  const int tid  = threadIdx.x;
  const int wave = tid >> 6;
  const int lane = tid & 63;
  const int lq   = lane & 15;
  const int quad = lane >> 4;
  const int bm = blockIdx.x, bn = blockIdx.y;
  const int wm = (wave >> 1) * (TM / 2), wn = (wave & 1) * (TN / 2);
  const int MT = TM / 32, NT = TN / 32;

  f32x4 acc[MT][NT];
#pragma unroll
  for (int i = 0; i < MT; ++i)
#pragma unroll
    for (int j = 0; j < NT; ++j) acc[i][j] = (f32x4){0.f, 0.f, 0.f, 0.f};

  const char* Ab = (const char*)(A + (size_t)bm * TM * K_DIM);
  const char* Bb = (const char*)(B + (size_t)bn * TN * K_DIM);

  for (int k0 = 0; k0 < K_DIM; k0 += 64) {
#pragma unroll
    for (int i = 0; i < MT; ++i) {
      int off   = i * 4096 + wave * 1024 + lane * 16;
      int row   = off >> 7;
      int chunk = (off >> 4) & 7;
      int scol  = (chunk ^ (row & 7)) << 4;
      gload16(Ab + (size_t)row * (K_DIM * 2) + (size_t)k0 * 2 + scol,
              (char*)Asm + off - lane * 16);
    }
#pragma unroll
    for (int i = 0; i < NT; ++i) {
      int off   = i * 4096 + wave * 1024 + lane * 16;
      int row   = off >> 7;
      int chunk = (off >> 4) & 7;
      int scol  = (chunk ^ (row & 7)) << 4;
      gload16(Bb + (size_t)row * (K_DIM * 2) + (size_t)k0 * 2 + scol,
              (char*)Bsm + off - lane * 16);
    }
    __syncthreads();
#pragma unroll
    for (int kk = 0; kk < 64; kk += 32) {
      bf16x8 af[MT], bfr[NT];
#pragma unroll
      for (int mt = 0; mt < MT; ++mt) {
        int row = wm + mt * 16 + lq;
        int sw  = (quad + (kk >> 3)) ^ (row & 7);
        af[mt] = *(const bf16x8*)((const char*)Asm + row * 128 + (sw << 4));
      }
#pragma unroll
      for (int nt = 0; nt < NT; ++nt) {
        int row = wn + nt * 16 + lq;
        int sw  = (quad + (kk >> 3)) ^ (row & 7);
        bfr[nt] = *(const bf16x8*)((const char*)Bsm + row * 128 + (sw << 4));
      }
#pragma unroll
      for (int mt = 0; mt < MT; ++mt)
#pragma unroll
        for (int nt = 0; nt < NT; ++nt)
          acc[mt][nt] = __builtin_amdgcn_mfma_f32_16x16x32_bf16(af[mt], bfr[nt], acc[mt][nt], 0, 0, 0);
    }
    __syncthreads();
  }

  // epilogues: acc r=0..3 are 4 consecutive m (chans)
#pragma unroll
  for (int mt = 0; mt < MT; ++mt) {
    int mbase = bm * TM + wm + mt * 16 + quad * 4;
#pragma unroll
    for (int nt = 0; nt < NT; ++nt) {
      int n = bn * TN + wn + nt * 16 + lq;
      if (MODE == 1) {
        int which = mbase >> 10, c = mbase & 1023;   // wave-uniform (1024 % TM == 0 per block)
        int h = c >> 6, d0 = c & 63;
        int b = n >> 11, t = n & 2047;
        if (which < 2) {
          ushort4 pk = pk4(acc[mt][nt][0], acc[mt][nt][1], acc[mt][nt][2], acc[mt][nt][3]);
          unsigned short* dst = which ? o_k : o_q;
          *(ushort4*)&dst[((size_t)(b * NH + h) * T + t) * HD + d0] = pk;
        } else {
          // vt[bh][d][t]: consecutive lanes -> consecutive t (coalesced segments)
#pragma unroll
          for (int r = 0; r < 4; ++r)
            o_v[((size_t)(b * NH + h) * HD + d0 + r) * T + t] = f2bf(acc[mt][nt][r]);
        }
      } else {
        float4 bv = *(const float4*)&bias[mbase];
        float4 o;
        o.x = acc[mt][nt][0] + bv.x; o.y = acc[mt][nt][1] + bv.y;
        o.z = acc[mt][nt][2] + bv.z; o.w = acc[mt][nt][3] + bv.w;
        *(float4*)&o_f[(size_t)n * K_DIM + mbase] = o;
      }
    }
  }
}

// ---------------- flash attention (S^T / O^T formulation) ----------------
// grid (32 bh, 16 q-tiles): XCD = linear%8 tracks bh -> all q-tiles of a bh
// hit the same XCD L2 (FETCH ~12MB measured). 256 threads; 32 q per wave.
// S^T = K Q^T -> lane's 4 C-regs = 4 consecutive keys -> P^T packs as b64 write.
// O^T = V^T P with full-width 128-key PV (single exp2/write/MFMA stretch for ILP).
// Padding int4 loads hoisted before the barrier (latency covered by staging).
// Scores pre-scaled (Wq carries 0.125*log2e) -> exp2 directly; no online max.
__global__ __launch_bounds__(256, 2)
void attn_kernel(const unsigned short* __restrict__ Q,
                 const unsigned short* __restrict__ Kb,
                 const unsigned short* __restrict__ Vt,
                 const int* __restrict__ padding,
                 unsigned short* __restrict__ O)
{
  __shared__ unsigned short Ksm[128 * 64];        // 16 KB [key][d], 128B rows, swiz &7
  __shared__ unsigned short Vsm[64 * 128];        // 16 KB [d][key], 256B rows, swiz &15
  __shared__ unsigned short Plds[4][32 * 32 * 4]; // 32 KB: per wave P^T[key/4][q] ushort4

  const int tid  = threadIdx.x;
  const int wave = tid >> 6;
  const int lane = tid & 63;
  const int lq   = lane & 15;
  const int quad = lane >> 4;
  const int bh = blockIdx.x;
  const int qt = blockIdx.y;
  const int b  = bh >> 4;
  const int h  = bh & 15;
  const int qbase = qt * 128 + wave * 32;

  // Q fragments (2nd operand): lane holds q = qbase+nq*16+lq, k = kk*32+quad*8+j
  bf16x8 qf[2][2];
#pragma unroll
  for (int nq = 0; nq < 2; ++nq)
#pragma unroll
    for (int kk = 0; kk < 2; ++kk)
      qf[nq][kk] = *(const bf16x8*)&Q[((size_t)bh * T + qbase + nq * 16 + lq) * HD + kk * 32 + quad * 8];

  f32x4 o_acc[4][2];   // [d-tile][q-tile]; O^T[d][q]
#pragma unroll
  for (int md = 0; md < 4; ++md)
#pragma unroll
    for (int nq = 0; nq < 2; ++nq) o_acc[md][nq] = (f32x4){0.f, 0.f, 0.f, 0.f};
  float l_part[2] = {0.f, 0.f};

  for (int kt = 0; kt < T / 128; ++kt) {
    // stage K-tile (128 keys x 64 d) and Vt-tile (64 d x 128 keys), swizzled
#pragma unroll
    for (int i = 0; i < 4; ++i) {
      int off = i * 4096 + wave * 1024 + lane * 16;
      {  // K: 128B rows
        int row = off >> 7, chunk = (off >> 4) & 7;
        int scol = (chunk ^ (row & 7)) << 4;
        gload16((const char*)Kb + ((size_t)(bh * T + kt * 128 + row) * HD) * 2 + scol,
                (char*)Ksm + off - lane * 16);
      }
      {  // Vt: 256B rows
        int row = off >> 8, chunk = (off >> 4) & 15;
        int scol = (chunk ^ (row & 15)) << 4;
        gload16((const char*)Vt + ((size_t)(bh * HD + row) * T + (size_t)kt * 128) * 2 + scol,
                (char*)Vsm + off - lane * 16);
      }
    }

    // padding loads hoisted here: latency covered by the staging window
    int4 pd[8];
#pragma unroll
    for (int nt = 0; nt < 8; ++nt)
      pd[nt] = *(const int4*)&padding[b * T + kt * 128 + nt * 16 + quad * 4];

    __syncthreads();

    // S^T = K Q^T : 128 keys x 32 q per wave; kf (from Ksm) feeds 2 MFMA
    f32x4 st[8][2];
#pragma unroll
    for (int nt = 0; nt < 8; ++nt)
#pragma unroll
      for (int nq = 0; nq < 2; ++nq) st[nt][nq] = (f32x4){0.f, 0.f, 0.f, 0.f};
#pragma unroll
    for (int kk = 0; kk < 2; ++kk) {
#pragma unroll
      for (int nt = 0; nt < 8; ++nt) {
        int row = nt * 16 + lq;
        int sw  = (quad + kk * 4) ^ (row & 7);
        bf16x8 kf = *(const bf16x8*)((const char*)Ksm + row * 128 + (sw << 4));
        st[nt][0] = __builtin_amdgcn_mfma_f32_16x16x32_bf16(kf, qf[0][kk], st[nt][0], 0, 0, 0);
        st[nt][1] = __builtin_amdgcn_mfma_f32_16x16x32_bf16(kf, qf[1][kk], st[nt][1], 0, 0, 0);
      }
    }

    // exp2 + padding mask + partial row sums; pack 4 consecutive keys -> b64 write
#pragma unroll
    for (int nt = 0; nt < 8; ++nt) {
#pragma unroll
      for (int nq = 0; nq < 2; ++nq) {
        float p0 = pd[nt].x ? __builtin_amdgcn_exp2f(st[nt][nq][0]) : 0.f;
        float p1 = pd[nt].y ? __builtin_amdgcn_exp2f(st[nt][nq][1]) : 0.f;
        float p2 = pd[nt].z ? __builtin_amdgcn_exp2f(st[nt][nq][2]) : 0.f;
        float p3 = pd[nt].w ? __builtin_amdgcn_exp2f(st[nt][nq][3]) : 0.f;
        l_part[nq] += (p0 + p1) + (p2 + p3);
        int row = nt * 4 + quad;          // key/4
        int col = nq * 16 + lq;           // q
        *(ushort4*)&Plds[wave][(row * 32 + col) * 4] = pk4(p0, p1, p2, p3);
      }
    }
    asm volatile("s_waitcnt lgkmcnt(0)" ::: "memory");

    // O^T += V^T P : vf (from Vsm) feeds 2 MFMA; P 2nd-operand via b64 pairs
#pragma unroll
    for (int kk = 0; kk < 4; ++kk) {   // 32-key chunks
      bf16x8 pf[2];
#pragma unroll
      for (int nq = 0; nq < 2; ++nq) {
        int row0 = kk * 8 + quad * 2;
        ushort4 lo = *(const ushort4*)&Plds[wave][((row0    ) * 32 + nq * 16 + lq) * 4];
        ushort4 hi = *(const ushort4*)&Plds[wave][((row0 + 1) * 32 + nq * 16 + lq) * 4];
        union { ushort4 u[2]; bf16x8 v; } cvt;
        cvt.u[0] = lo; cvt.u[1] = hi;
        pf[nq] = cvt.v;
      }
#pragma unroll
      for (int md = 0; md < 4; ++md) {
        int row = md * 16 + lq;
        int sw  = ((kk * 4 + quad) ^ (row & 15)) << 4;
        bf16x8 vf = *(const bf16x8*)((const char*)Vsm + row * 256 + sw);
        o_acc[md][0] = __builtin_amdgcn_mfma_f32_16x16x32_bf16(vf, pf[0], o_acc[md][0], 0, 0, 0);
        o_acc[md][1] = __builtin_amdgcn_mfma_f32_16x16x32_bf16(vf, pf[1], o_acc[md][1], 0, 0, 0);
      }
    }
    __syncthreads();
  }

  // epilogue: reduce l over the 4 quads (keys), normalize, packed ushort4 stores
  float inv[2];
#pragma unroll
  for (int nq = 0; nq < 2; ++nq) {
    float lsum = l_part[nq];
    lsum += __shfl_xor(lsum, 16);
    lsum += __shfl_xor(lsum, 32);
    inv[nq] = (lsum > 0.f) ? 1.f / lsum : 0.f;
  }
#pragma unroll
  for (int md = 0; md < 4; ++md) {
#pragma unroll
    for (int nq = 0; nq < 2; ++nq) {
      int t = qbase + nq * 16 + lq;
      int chan0 = h * HD + md * 16 + quad * 4;
      *(ushort4*)&O[((size_t)(b * T + t)) * K_DIM + chan0] =
          pk4(o_acc[md][nq][0] * inv[nq], o_acc[md][nq][1] * inv[nq],
              o_acc[md][nq][2] * inv[nq], o_acc[md][nq][3] * inv[nq]);
    }
  }
}

// ---------------- launch ----------------
extern "C" void kernel_launch(void* const* d_in, const int* in_sizes, int n_in,
                              void* d_out, int out_size, void* d_ws, size_t ws_size,
                              hipStream_t stream)
{
  const float* x       = (const float*)d_in[0];
  const int*   padding = (const int*)d_in[1];
  const float* Wq      = (const float*)d_in[2];
  const float* Wk      = (const float*)d_in[3];
  const float* Wv      = (const float*)d_in[4];
  const float* Wo      = (const float*)d_in[5];
  const float* bo      = (const float*)d_in[6];
  float* out = (float*)d_out;

  char* ws = (char*)d_ws;
  unsigned short* xb   = (unsigned short*)(ws);                 // 8 MB  x bf16 [4096][1024]
  unsigned short* wqkv = (unsigned short*)(ws + (8u  << 20));   // 6 MB  [Wq;Wk;Wv] bf16
  unsigned short* wob  = (unsigned short*)(ws + (14u << 20));   // 2 MB  Wo bf16
  unsigned short* qb   = (unsigned short*)(ws + (16u << 20));   // 8 MB  q [bh][t][d] (pre-scaled)
  unsigned short* kb   = (unsigned short*)(ws + (24u << 20));   // 8 MB  k [bh][t][d]
  unsigned short* vtb  = (unsigned short*)(ws + (32u << 20));   // 8 MB  v^T [bh][d][t]
  unsigned short* ab   = (unsigned short*)(ws + (40u << 20));   // 8 MB  attn-out [b*t][1024]

  convert_kernel<<<8192, 256, 0, stream>>>(x, Wq, Wk, Wv, Wo, xb, wqkv, wob);

  // fused Q,K,V projections: C[3072 chans][4096 tokens] = [Wq;Wk;Wv] @ x^T
  gemm_bt<1, 128, 128><<<dim3(24, 32), 256, 0, stream>>>(wqkv, xb, qb, kb, vtb, nullptr, nullptr);

  // attention
  attn_kernel<<<dim3(32, 16), 256, 0, stream>>>(qb, kb, vtb, padding, ab);

  // output projection: C[1024 chans][4096 tokens] = Wo @ attn^T -> out[t][chan]+bo
  gemm_bt<2, 64, 128><<<dim3(16, 32), 256, 0, stream>>>(wob, ab, nullptr, nullptr, nullptr, out, bo);
}

// Round 9
// 188.344 us; speedup vs baseline: 1.0551x; 1.0551x over previous
//
#include <hip/hip_runtime.h>
#include <hip/hip_bf16.h>
#include <cmath>
#include <stdint.h>

// ---------------- problem constants ----------------
#define K_DIM 1024
#define NH    16
#define HD    64
#define T     2048
#define NTOK  4096   // b*t = 2*2048
#define NBH   32     // b*h

typedef __bf16 bf16x8 __attribute__((ext_vector_type(8)));
typedef float  f32x4  __attribute__((ext_vector_type(4)));

__device__ __forceinline__ unsigned short f2bf(float f) {
  union { float f; unsigned u; } v; v.f = f;
  unsigned u = v.u;
  return (unsigned short)((u + 0x7FFFu + ((u >> 16) & 1u)) >> 16);
}
// packed round-nearest-even via v_cvt_pk_bf16_f32
__device__ __forceinline__ ushort4 pk4(float a, float b, float c, float d) {
  union { __hip_bfloat162 h[2]; ushort4 u; } r;
  r.h[0] = __float22bfloat162_rn(float2{a, b});
  r.h[1] = __float22bfloat162_rn(float2{c, d});
  return r.u;
}

__device__ __forceinline__ void gload16(const void* g, void* l) {
  __builtin_amdgcn_global_load_lds(
      (__attribute__((address_space(1))) void*)(g),
      (__attribute__((address_space(3))) void*)(l),
      16, 0, 0);
}

// ---------------- fp32 -> bf16 conversion ----------------
// Wq is pre-scaled by 0.125*log2(e) so attn can exp2() scores directly.
__global__ void convert_kernel(const float* __restrict__ x,
                               const float* __restrict__ Wq,
                               const float* __restrict__ Wk,
                               const float* __restrict__ Wv,
                               const float* __restrict__ Wo,
                               unsigned short* __restrict__ xb,
                               unsigned short* __restrict__ wqkv,
                               unsigned short* __restrict__ wob)
{
  const size_t NX = (size_t)NTOK * K_DIM;   // 4M
  const size_t NW = (size_t)K_DIM * K_DIM;  // 1M
  size_t i = ((size_t)blockIdx.x * blockDim.x + threadIdx.x) * 4;
  const float* src; unsigned short* dst; size_t off;
  float scale = 1.f;
  if (i < NX)             { src = x;  dst = xb;          off = i; }
  else if (i < NX + NW)   { src = Wq; dst = wqkv;        off = i - NX;
                            scale = 0.18033688011112042f; }
  else if (i < NX + 2*NW) { src = Wk; dst = wqkv + NW;   off = i - NX - NW; }
  else if (i < NX + 3*NW) { src = Wv; dst = wqkv + 2*NW; off = i - NX - 2*NW; }
  else                    { src = Wo; dst = wob;         off = i - NX - 3*NW; }
  float4 v = *(const float4*)(src + off);
  *(ushort4*)(dst + off) = pk4(v.x * scale, v.y * scale, v.z * scale, v.w * scale);
}

// ---------------- B^T GEMM: C[m][n] = sum_k A[m*1024+k] * B[n*1024+k] ----------------
// TMxTN tile, BK=64, 256 threads (2x2 waves). XOR-swizzled LDS (chunk ^= row&7).
// MODE 1 (fused QKV): A=[Wq;Wk;Wv], m=chan in [0,3072), n=token.
//   q/k: packed ushort4 along d; v: b16 scatter to vt[bh][d][t] (t-coalesced).
// MODE 2 (out-proj):  A=Wo, m=chan in [0,1024), n=token -> out[t][chan]+bias, float4.
template <int MODE, int TM, int TN>
__global__ __launch_bounds__(256, 2)
void gemm_bt(const unsigned short* __restrict__ A,
             const unsigned short* __restrict__ B,
             unsigned short* __restrict__ o_q,
             unsigned short* __restrict__ o_k,
             unsigned short* __restrict__ o_v,
             float* __restrict__ o_f,
             const float* __restrict__ bias)
{
  __shared__ unsigned short Asm[TM * 64];
  __shared__ unsigned short Bsm[TN * 64];
  const int tid  = threadIdx.x;
  const int wave = tid >> 6;
  const int lane = tid & 63;
  const int lq   = lane & 15;
  const int quad = lane >> 4;
  const int bm = blockIdx.x, bn = blockIdx.y;
  const int wm = (wave >> 1) * (TM / 2), wn = (wave & 1) * (TN / 2);
  const int MT = TM / 32, NT = TN / 32;

  f32x4 acc[MT][NT];
#pragma unroll
  for (int i = 0; i < MT; ++i)
#pragma unroll
    for (int j = 0; j < NT; ++j) acc[i][j] = (f32x4){0.f, 0.f, 0.f, 0.f};

  const char* Ab = (const char*)(A + (size_t)bm * TM * K_DIM);
  const char* Bb = (const char*)(B + (size_t)bn * TN * K_DIM);

  for (int k0 = 0; k0 < K_DIM; k0 += 64) {
#pragma unroll
    for (int i = 0; i < MT; ++i) {
      int off   = i * 4096 + wave * 1024 + lane * 16;
      int row   = off >> 7;
      int chunk = (off >> 4) & 7;
      int scol  = (chunk ^ (row & 7)) << 4;
      gload16(Ab + (size_t)row * (K_DIM * 2) + (size_t)k0 * 2 + scol,
              (char*)Asm + off - lane * 16);
    }
#pragma unroll
    for (int i = 0; i < NT; ++i) {
      int off   = i * 4096 + wave * 1024 + lane * 16;
      int row   = off >> 7;
      int chunk = (off >> 4) & 7;
      int scol  = (chunk ^ (row & 7)) << 4;
      gload16(Bb + (size_t)row * (K_DIM * 2) + (size_t)k0 * 2 + scol,
              (char*)Bsm + off - lane * 16);
    }
    __syncthreads();
#pragma unroll
    for (int kk = 0; kk < 64; kk += 32) {
      bf16x8 af[MT], bfr[NT];
#pragma unroll
      for (int mt = 0; mt < MT; ++mt) {
        int row = wm + mt * 16 + lq;
        int sw  = (quad + (kk >> 3)) ^ (row & 7);
        af[mt] = *(const bf16x8*)((const char*)Asm + row * 128 + (sw << 4));
      }
#pragma unroll
      for (int nt = 0; nt < NT; ++nt) {
        int row = wn + nt * 16 + lq;
        int sw  = (quad + (kk >> 3)) ^ (row & 7);
        bfr[nt] = *(const bf16x8*)((const char*)Bsm + row * 128 + (sw << 4));
      }
#pragma unroll
      for (int mt = 0; mt < MT; ++mt)
#pragma unroll
        for (int nt = 0; nt < NT; ++nt)
          acc[mt][nt] = __builtin_amdgcn_mfma_f32_16x16x32_bf16(af[mt], bfr[nt], acc[mt][nt], 0, 0, 0);
    }
    __syncthreads();
  }

  // epilogues: acc r=0..3 are 4 consecutive m (chans)
#pragma unroll
  for (int mt = 0; mt < MT; ++mt) {
    int mbase = bm * TM + wm + mt * 16 + quad * 4;
#pragma unroll
    for (int nt = 0; nt < NT; ++nt) {
      int n = bn * TN + wn + nt * 16 + lq;
      if (MODE == 1) {
        int which = mbase >> 10, c = mbase & 1023;   // wave-uniform (1024 % TM == 0 per block)
        int h = c >> 6, d0 = c & 63;
        int b = n >> 11, t = n & 2047;
        if (which < 2) {
          ushort4 pk = pk4(acc[mt][nt][0], acc[mt][nt][1], acc[mt][nt][2], acc[mt][nt][3]);
          unsigned short* dst = which ? o_k : o_q;
          *(ushort4*)&dst[((size_t)(b * NH + h) * T + t) * HD + d0] = pk;
        } else {
          // vt[bh][d][t]: consecutive lanes -> consecutive t (coalesced segments)
#pragma unroll
          for (int r = 0; r < 4; ++r)
            o_v[((size_t)(b * NH + h) * HD + d0 + r) * T + t] = f2bf(acc[mt][nt][r]);
        }
      } else {
        float4 bv = *(const float4*)&bias[mbase];
        float4 o;
        o.x = acc[mt][nt][0] + bv.x; o.y = acc[mt][nt][1] + bv.y;
        o.z = acc[mt][nt][2] + bv.z; o.w = acc[mt][nt][3] + bv.w;
        *(float4*)&o_f[(size_t)n * K_DIM + mbase] = o;
      }
    }
  }
}

// ---------------- flash attention (S^T / O^T formulation) ----------------
// grid (32 bh, 16 q-tiles): XCD = linear%8 tracks bh -> all q-tiles of a bh
// hit the same XCD L2 (FETCH ~12MB measured). 256 threads; 32 q per wave.
// S^T = K Q^T -> lane's 4 C-regs = 4 consecutive keys -> P^T packs as b64 write.
// O^T = V^T P, full-width 128-key PV; P re-read as single b128 per 32-key chunk
// (Plds layout [key/8][q][2xushort4]). Padding int4 loads stay inside the exp
// loop (hoisting them into the staging window measured -5us). Scores are
// pre-scaled (Wq carries 0.125*log2e) -> exp2 directly; no online max.
__global__ __launch_bounds__(256, 2)
void attn_kernel(const unsigned short* __restrict__ Q,
                 const unsigned short* __restrict__ Kb,
                 const unsigned short* __restrict__ Vt,
                 const int* __restrict__ padding,
                 unsigned short* __restrict__ O)
{
  __shared__ unsigned short Ksm[128 * 64];        // 16 KB [key][d], 128B rows, swiz &7
  __shared__ unsigned short Vsm[64 * 128];        // 16 KB [d][key], 256B rows, swiz &15
  __shared__ unsigned short Plds[4][16 * 32 * 8]; // 32 KB: per wave [key/8][q][8]

  const int tid  = threadIdx.x;
  const int wave = tid >> 6;
  const int lane = tid & 63;
  const int lq   = lane & 15;
  const int quad = lane >> 4;
  const int bh = blockIdx.x;
  const int qt = blockIdx.y;
  const int b  = bh >> 4;
  const int h  = bh & 15;
  const int qbase = qt * 128 + wave * 32;

  // Q fragments (2nd operand): lane holds q = qbase+nq*16+lq, k = kk*32+quad*8+j
  bf16x8 qf[2][2];
#pragma unroll
  for (int nq = 0; nq < 2; ++nq)
#pragma unroll
    for (int kk = 0; kk < 2; ++kk)
      qf[nq][kk] = *(const bf16x8*)&Q[((size_t)bh * T + qbase + nq * 16 + lq) * HD + kk * 32 + quad * 8];

  f32x4 o_acc[4][2];   // [d-tile][q-tile]; O^T[d][q]
#pragma unroll
  for (int md = 0; md < 4; ++md)
#pragma unroll
    for (int nq = 0; nq < 2; ++nq) o_acc[md][nq] = (f32x4){0.f, 0.f, 0.f, 0.f};
  float l_part[2] = {0.f, 0.f};

  for (int kt = 0; kt < T / 128; ++kt) {
    // stage K-tile (128 keys x 64 d) and Vt-tile (64 d x 128 keys), swizzled
#pragma unroll
    for (int i = 0; i < 4; ++i) {
      int off = i * 4096 + wave * 1024 + lane * 16;
      {  // K: 128B rows
        int row = off >> 7, chunk = (off >> 4) & 7;
        int scol = (chunk ^ (row & 7)) << 4;
        gload16((const char*)Kb + ((size_t)(bh * T + kt * 128 + row) * HD) * 2 + scol,
                (char*)Ksm + off - lane * 16);
      }
      {  // Vt: 256B rows
        int row = off >> 8, chunk = (off >> 4) & 15;
        int scol = (chunk ^ (row & 15)) << 4;
        gload16((const char*)Vt + ((size_t)(bh * HD + row) * T + (size_t)kt * 128) * 2 + scol,
                (char*)Vsm + off - lane * 16);
      }
    }
    __syncthreads();

    // S^T = K Q^T : 128 keys x 32 q per wave; kf (from Ksm) feeds 2 MFMA
    f32x4 st[8][2];
#pragma unroll
    for (int nt = 0; nt < 8; ++nt)
#pragma unroll
      for (int nq = 0; nq < 2; ++nq) st[nt][nq] = (f32x4){0.f, 0.f, 0.f, 0.f};
#pragma unroll
    for (int kk = 0; kk < 2; ++kk) {
#pragma unroll
      for (int nt = 0; nt < 8; ++nt) {
        int row = nt * 16 + lq;
        int sw  = (quad + kk * 4) ^ (row & 7);
        bf16x8 kf = *(const bf16x8*)((const char*)Ksm + row * 128 + (sw << 4));
        st[nt][0] = __builtin_amdgcn_mfma_f32_16x16x32_bf16(kf, qf[0][kk], st[nt][0], 0, 0, 0);
        st[nt][1] = __builtin_amdgcn_mfma_f32_16x16x32_bf16(kf, qf[1][kk], st[nt][1], 0, 0, 0);
      }
    }

    // exp2 + padding mask + partial row sums; pack 4 consecutive keys -> b64 write
    // Plds index: ((key>>3)*32 + q)*8 + (key>>2 & 1)*4
#pragma unroll
    for (int nt = 0; nt < 8; ++nt) {
      int4 pd = *(const int4*)&padding[b * T + kt * 128 + nt * 16 + quad * 4];
      int row  = nt * 4 + quad;          // key/4
      int base = ((row >> 1) * 32) * 8 + (row & 1) * 4;
#pragma unroll
      for (int nq = 0; nq < 2; ++nq) {
        float p0 = pd.x ? __builtin_amdgcn_exp2f(st[nt][nq][0]) : 0.f;
        float p1 = pd.y ? __builtin_amdgcn_exp2f(st[nt][nq][1]) : 0.f;
        float p2 = pd.z ? __builtin_amdgcn_exp2f(st[nt][nq][2]) : 0.f;
        float p3 = pd.w ? __builtin_amdgcn_exp2f(st[nt][nq][3]) : 0.f;
        l_part[nq] += (p0 + p1) + (p2 + p3);
        int col = nq * 16 + lq;           // q
        *(ushort4*)&Plds[wave][base + col * 8] = pk4(p0, p1, p2, p3);
      }
    }
    asm volatile("s_waitcnt lgkmcnt(0)" ::: "memory");

    // O^T += V^T P : vf (from Vsm) feeds 2 MFMA; P 2nd-operand via one b128
#pragma unroll
    for (int kk = 0; kk < 4; ++kk) {   // 32-key chunks
      bf16x8 pf[2];
#pragma unroll
      for (int nq = 0; nq < 2; ++nq) {
        int krow8 = kk * 4 + quad;      // key/8
        pf[nq] = *(const bf16x8*)&Plds[wave][(krow8 * 32 + nq * 16 + lq) * 8];
      }
#pragma unroll
      for (int md = 0; md < 4; ++md) {
        int row = md * 16 + lq;
        int sw  = ((kk * 4 + quad) ^ (row & 15)) << 4;
        bf16x8 vf = *(const bf16x8*)((const char*)Vsm + row * 256 + sw);
        o_acc[md][0] = __builtin_amdgcn_mfma_f32_16x16x32_bf16(vf, pf[0], o_acc[md][0], 0, 0, 0);
        o_acc[md][1] = __builtin_amdgcn_mfma_f32_16x16x32_bf16(vf, pf[1], o_acc[md][1], 0, 0, 0);
      }
    }
    __syncthreads();
  }

  // epilogue: reduce l over the 4 quads (keys), normalize, packed ushort4 stores
  float inv[2];
#pragma unroll
  for (int nq = 0; nq < 2; ++nq) {
    float lsum = l_part[nq];
    lsum += __shfl_xor(lsum, 16);
    lsum += __shfl_xor(lsum, 32);
    inv[nq] = (lsum > 0.f) ? 1.f / lsum : 0.f;
  }
#pragma unroll
  for (int md = 0; md < 4; ++md) {
#pragma unroll
    for (int nq = 0; nq < 2; ++nq) {
      int t = qbase + nq * 16 + lq;
      int chan0 = h * HD + md * 16 + quad * 4;
      *(ushort4*)&O[((size_t)(b * T + t)) * K_DIM + chan0] =
          pk4(o_acc[md][nq][0] * inv[nq], o_acc[md][nq][1] * inv[nq],
              o_acc[md][nq][2] * inv[nq], o_acc[md][nq][3] * inv[nq]);
    }
  }
}

// ---------------- launch ----------------
extern "C" void kernel_launch(void* const* d_in, const int* in_sizes, int n_in,
                              void* d_out, int out_size, void* d_ws, size_t ws_size,
                              hipStream_t stream)
{
  const float* x       = (const float*)d_in[0];
  const int*   padding = (const int*)d_in[1];
  const float* Wq      = (const float*)d_in[2];
  const float* Wk      = (const float*)d_in[3];
  const float* Wv      = (const float*)d_in[4];
  const float* Wo      = (const float*)d_in[5];
  const float* bo      = (const float*)d_in[6];
  float* out = (float*)d_out;

  char* ws = (char*)d_ws;
  unsigned short* xb   = (unsigned short*)(ws);                 // 8 MB  x bf16 [4096][1024]
  unsigned short* wqkv = (unsigned short*)(ws + (8u  << 20));   // 6 MB  [Wq;Wk;Wv] bf16
  unsigned short* wob  = (unsigned short*)(ws + (14u << 20));   // 2 MB  Wo bf16
  unsigned short* qb   = (unsigned short*)(ws + (16u << 20));   // 8 MB  q [bh][t][d] (pre-scaled)
  unsigned short* kb   = (unsigned short*)(ws + (24u << 20));   // 8 MB  k [bh][t][d]
  unsigned short* vtb  = (unsigned short*)(ws + (32u << 20));   // 8 MB  v^T [bh][d][t]
  unsigned short* ab   = (unsigned short*)(ws + (40u << 20));   // 8 MB  attn-out [b*t][1024]

  convert_kernel<<<8192, 256, 0, stream>>>(x, Wq, Wk, Wv, Wo, xb, wqkv, wob);

  // fused Q,K,V projections: C[3072 chans][4096 tokens] = [Wq;Wk;Wv] @ x^T
  gemm_bt<1, 128, 128><<<dim3(24, 32), 256, 0, stream>>>(wqkv, xb, qb, kb, vtb, nullptr, nullptr);

  // attention
  attn_kernel<<<dim3(32, 16), 256, 0, stream>>>(qb, kb, vtb, padding, ab);

  // output projection: C[1024 chans][4096 tokens] = Wo @ attn^T -> out[t][chan]+bo
  gemm_bt<2, 64, 128><<<dim3(16, 32), 256, 0, stream>>>(wob, ab, nullptr, nullptr, nullptr, out, bo);
}

// Round 10
// 186.792 us; speedup vs baseline: 1.0639x; 1.0083x over previous
//
#include <hip/hip_runtime.h>
#include <hip/hip_bf16.h>
#include <cmath>
#include <stdint.h>

// ---------------- problem constants ----------------
#define K_DIM 1024
#define NH    16
#define HD    64
#define T     2048
#define NTOK  4096   // b*t = 2*2048
#define NBH   32     // b*h

typedef __bf16 bf16x8 __attribute__((ext_vector_type(8)));
typedef float  f32x4  __attribute__((ext_vector_type(4)));

__device__ __forceinline__ unsigned short f2bf(float f) {
  union { float f; unsigned u; } v; v.f = f;
  unsigned u = v.u;
  return (unsigned short)((u + 0x7FFFu + ((u >> 16) & 1u)) >> 16);
}
// packed round-nearest-even via v_cvt_pk_bf16_f32
__device__ __forceinline__ ushort4 pk4(float a, float b, float c, float d) {
  union { __hip_bfloat162 h[2]; ushort4 u; } r;
  r.h[0] = __float22bfloat162_rn(float2{a, b});
  r.h[1] = __float22bfloat162_rn(float2{c, d});
  return r.u;
}

__device__ __forceinline__ void gload16(const void* g, void* l) {
  __builtin_amdgcn_global_load_lds(
      (__attribute__((address_space(1))) void*)(g),
      (__attribute__((address_space(3))) void*)(l),
      16, 0, 0);
}

// ---------------- fp32 -> bf16 conversion ----------------
// Wq is pre-scaled by 0.125*log2(e) so attn can exp2() scores directly.
__global__ void convert_kernel(const float* __restrict__ x,
                               const float* __restrict__ Wq,
                               const float* __restrict__ Wk,
                               const float* __restrict__ Wv,
                               const float* __restrict__ Wo,
                               unsigned short* __restrict__ xb,
                               unsigned short* __restrict__ wqkv,
                               unsigned short* __restrict__ wob)
{
  const size_t NX = (size_t)NTOK * K_DIM;   // 4M
  const size_t NW = (size_t)K_DIM * K_DIM;  // 1M
  size_t i = ((size_t)blockIdx.x * blockDim.x + threadIdx.x) * 4;
  const float* src; unsigned short* dst; size_t off;
  float scale = 1.f;
  if (i < NX)             { src = x;  dst = xb;          off = i; }
  else if (i < NX + NW)   { src = Wq; dst = wqkv;        off = i - NX;
                            scale = 0.18033688011112042f; }
  else if (i < NX + 2*NW) { src = Wk; dst = wqkv + NW;   off = i - NX - NW; }
  else if (i < NX + 3*NW) { src = Wv; dst = wqkv + 2*NW; off = i - NX - 2*NW; }
  else                    { src = Wo; dst = wob;         off = i - NX - 3*NW; }
  float4 v = *(const float4*)(src + off);
  *(ushort4*)(dst + off) = pk4(v.x * scale, v.y * scale, v.z * scale, v.w * scale);
}

// ---------------- B^T GEMM: C[m][n] = sum_k A[m*1024+k] * B[n*1024+k] ----------------
// TMxTN tile, BK=64, 256 threads (2x2 waves). XOR-swizzled LDS (chunk ^= row&7).
// MODE 1 (fused QKV): A=[Wq;Wk;Wv], m=chan in [0,3072), n=token; TM=192 for
//   balanced LDS:MFMA (10 b128 reads per 24 MFMA per kk-step).
//   q/k: packed ushort4 along d; v: b16 scatter to vt[bh][d][t] (t-coalesced).
// MODE 2 (out-proj):  A=Wo, m=chan in [0,1024), n=token -> out[t][chan]+bias, float4.
template <int MODE, int TM, int TN>
__global__ __launch_bounds__(256, 2)
void gemm_bt(const unsigned short* __restrict__ A,
             const unsigned short* __restrict__ B,
             unsigned short* __restrict__ o_q,
             unsigned short* __restrict__ o_k,
             unsigned short* __restrict__ o_v,
             float* __restrict__ o_f,
             const float* __restrict__ bias)
{
  __shared__ unsigned short Asm[TM * 64];
  __shared__ unsigned short Bsm[TN * 64];
  const int tid  = threadIdx.x;
  const int wave = tid >> 6;
  const int lane = tid & 63;
  const int lq   = lane & 15;
  const int quad = lane >> 4;
  const int bm = blockIdx.x, bn = blockIdx.y;
  const int wm = (wave >> 1) * (TM / 2), wn = (wave & 1) * (TN / 2);
  const int MT = TM / 32, NT = TN / 32;

  f32x4 acc[MT][NT];
#pragma unroll
  for (int i = 0; i < MT; ++i)
#pragma unroll
    for (int j = 0; j < NT; ++j) acc[i][j] = (f32x4){0.f, 0.f, 0.f, 0.f};

  const char* Ab = (const char*)(A + (size_t)bm * TM * K_DIM);
  const char* Bb = (const char*)(B + (size_t)bn * TN * K_DIM);

  for (int k0 = 0; k0 < K_DIM; k0 += 64) {
#pragma unroll
    for (int i = 0; i < MT; ++i) {
      int off   = i * 4096 + wave * 1024 + lane * 16;
      int row   = off >> 7;
      int chunk = (off >> 4) & 7;
      int scol  = (chunk ^ (row & 7)) << 4;
      gload16(Ab + (size_t)row * (K_DIM * 2) + (size_t)k0 * 2 + scol,
              (char*)Asm + off - lane * 16);
    }
#pragma unroll
    for (int i = 0; i < NT; ++i) {
      int off   = i * 4096 + wave * 1024 + lane * 16;
      int row   = off >> 7;
      int chunk = (off >> 4) & 7;
      int scol  = (chunk ^ (row & 7)) << 4;
      gload16(Bb + (size_t)row * (K_DIM * 2) + (size_t)k0 * 2 + scol,
              (char*)Bsm + off - lane * 16);
    }
    __syncthreads();
#pragma unroll
    for (int kk = 0; kk < 64; kk += 32) {
      bf16x8 af[MT], bfr[NT];
#pragma unroll
      for (int mt = 0; mt < MT; ++mt) {
        int row = wm + mt * 16 + lq;
        int sw  = (quad + (kk >> 3)) ^ (row & 7);
        af[mt] = *(const bf16x8*)((const char*)Asm + row * 128 + (sw << 4));
      }
#pragma unroll
      for (int nt = 0; nt < NT; ++nt) {
        int row = wn + nt * 16 + lq;
        int sw  = (quad + (kk >> 3)) ^ (row & 7);
        bfr[nt] = *(const bf16x8*)((const char*)Bsm + row * 128 + (sw << 4));
      }
#pragma unroll
      for (int mt = 0; mt < MT; ++mt)
#pragma unroll
        for (int nt = 0; nt < NT; ++nt)
          acc[mt][nt] = __builtin_amdgcn_mfma_f32_16x16x32_bf16(af[mt], bfr[nt], acc[mt][nt], 0, 0, 0);
    }
    __syncthreads();
  }

  // epilogues: acc r=0..3 are 4 consecutive m (chans)
#pragma unroll
  for (int mt = 0; mt < MT; ++mt) {
    int mbase = bm * TM + wm + mt * 16 + quad * 4;
#pragma unroll
    for (int nt = 0; nt < NT; ++nt) {
      int n = bn * TN + wn + nt * 16 + lq;
      if (MODE == 1) {
        int which = mbase >> 10, c = mbase & 1023;   // uniform per 16-row tile
        int h = c >> 6, d0 = c & 63;
        int b = n >> 11, t = n & 2047;
        if (which < 2) {
          ushort4 pk = pk4(acc[mt][nt][0], acc[mt][nt][1], acc[mt][nt][2], acc[mt][nt][3]);
          unsigned short* dst = which ? o_k : o_q;
          *(ushort4*)&dst[((size_t)(b * NH + h) * T + t) * HD + d0] = pk;
        } else {
          // vt[bh][d][t]: consecutive lanes -> consecutive t (coalesced segments)
#pragma unroll
          for (int r = 0; r < 4; ++r)
            o_v[((size_t)(b * NH + h) * HD + d0 + r) * T + t] = f2bf(acc[mt][nt][r]);
        }
      } else {
        float4 bv = *(const float4*)&bias[mbase];
        float4 o;
        o.x = acc[mt][nt][0] + bv.x; o.y = acc[mt][nt][1] + bv.y;
        o.z = acc[mt][nt][2] + bv.z; o.w = acc[mt][nt][3] + bv.w;
        *(float4*)&o_f[(size_t)n * K_DIM + mbase] = o;
      }
    }
  }
}

// ---------------- flash attention (S^T / O^T formulation) ----------------
// grid (32 bh, 16 q-tiles): XCD = linear%8 tracks bh -> all q-tiles of a bh
// hit the same XCD L2 (FETCH ~12MB measured). 256 threads; 32 q per wave.
// S^T = K Q^T -> lane's 4 C-regs = 4 consecutive keys -> P^T packs as b64 write.
// O^T = V^T P, full-width 128-key PV; P re-read as 2x b64 (conflict-free R7
// layout — the b128 variant measured identical time but 2.1e6 bank conflicts).
// Padding int4 loads stay inside the exp loop (hoisting measured -5us).
// Scores pre-scaled (Wq carries 0.125*log2e) -> exp2 directly; no online max.
__global__ __launch_bounds__(256, 2)
void attn_kernel(const unsigned short* __restrict__ Q,
                 const unsigned short* __restrict__ Kb,
                 const unsigned short* __restrict__ Vt,
                 const int* __restrict__ padding,
                 unsigned short* __restrict__ O)
{
  __shared__ unsigned short Ksm[128 * 64];        // 16 KB [key][d], 128B rows, swiz &7
  __shared__ unsigned short Vsm[64 * 128];        // 16 KB [d][key], 256B rows, swiz &15
  __shared__ unsigned short Plds[4][32 * 32 * 4]; // 32 KB: per wave P^T[key/4][q] ushort4

  const int tid  = threadIdx.x;
  const int wave = tid >> 6;
  const int lane = tid & 63;
  const int lq   = lane & 15;
  const int quad = lane >> 4;
  const int bh = blockIdx.x;
  const int qt = blockIdx.y;
  const int b  = bh >> 4;
  const int h  = bh & 15;
  const int qbase = qt * 128 + wave * 32;

  // Q fragments (2nd operand): lane holds q = qbase+nq*16+lq, k = kk*32+quad*8+j
  bf16x8 qf[2][2];
#pragma unroll
  for (int nq = 0; nq < 2; ++nq)
#pragma unroll
    for (int kk = 0; kk < 2; ++kk)
      qf[nq][kk] = *(const bf16x8*)&Q[((size_t)bh * T + qbase + nq * 16 + lq) * HD + kk * 32 + quad * 8];

  f32x4 o_acc[4][2];   // [d-tile][q-tile]; O^T[d][q]
#pragma unroll
  for (int md = 0; md < 4; ++md)
#pragma unroll
    for (int nq = 0; nq < 2; ++nq) o_acc[md][nq] = (f32x4){0.f, 0.f, 0.f, 0.f};
  float l_part[2] = {0.f, 0.f};

  for (int kt = 0; kt < T / 128; ++kt) {
    // stage K-tile (128 keys x 64 d) and Vt-tile (64 d x 128 keys), swizzled
#pragma unroll
    for (int i = 0; i < 4; ++i) {
      int off = i * 4096 + wave * 1024 + lane * 16;
      {  // K: 128B rows
        int row = off >> 7, chunk = (off >> 4) & 7;
        int scol = (chunk ^ (row & 7)) << 4;
        gload16((const char*)Kb + ((size_t)(bh * T + kt * 128 + row) * HD) * 2 + scol,
                (char*)Ksm + off - lane * 16);
      }
      {  // Vt: 256B rows
        int row = off >> 8, chunk = (off >> 4) & 15;
        int scol = (chunk ^ (row & 15)) << 4;
        gload16((const char*)Vt + ((size_t)(bh * HD + row) * T + (size_t)kt * 128) * 2 + scol,
                (char*)Vsm + off - lane * 16);
      }
    }
    __syncthreads();

    // S^T = K Q^T : 128 keys x 32 q per wave; kf (from Ksm) feeds 2 MFMA
    f32x4 st[8][2];
#pragma unroll
    for (int nt = 0; nt < 8; ++nt)
#pragma unroll
      for (int nq = 0; nq < 2; ++nq) st[nt][nq] = (f32x4){0.f, 0.f, 0.f, 0.f};
#pragma unroll
    for (int kk = 0; kk < 2; ++kk) {
#pragma unroll
      for (int nt = 0; nt < 8; ++nt) {
        int row = nt * 16 + lq;
        int sw  = (quad + kk * 4) ^ (row & 7);
        bf16x8 kf = *(const bf16x8*)((const char*)Ksm + row * 128 + (sw << 4));
        st[nt][0] = __builtin_amdgcn_mfma_f32_16x16x32_bf16(kf, qf[0][kk], st[nt][0], 0, 0, 0);
        st[nt][1] = __builtin_amdgcn_mfma_f32_16x16x32_bf16(kf, qf[1][kk], st[nt][1], 0, 0, 0);
      }
    }

    // exp2 + padding mask + partial row sums; pack 4 consecutive keys -> b64 write
#pragma unroll
    for (int nt = 0; nt < 8; ++nt) {
      int4 pd = *(const int4*)&padding[b * T + kt * 128 + nt * 16 + quad * 4];
#pragma unroll
      for (int nq = 0; nq < 2; ++nq) {
        float p0 = pd.x ? __builtin_amdgcn_exp2f(st[nt][nq][0]) : 0.f;
        float p1 = pd.y ? __builtin_amdgcn_exp2f(st[nt][nq][1]) : 0.f;
        float p2 = pd.z ? __builtin_amdgcn_exp2f(st[nt][nq][2]) : 0.f;
        float p3 = pd.w ? __builtin_amdgcn_exp2f(st[nt][nq][3]) : 0.f;
        l_part[nq] += (p0 + p1) + (p2 + p3);
        int row = nt * 4 + quad;          // key/4
        int col = nq * 16 + lq;           // q
        *(ushort4*)&Plds[wave][(row * 32 + col) * 4] = pk4(p0, p1, p2, p3);
      }
    }
    asm volatile("s_waitcnt lgkmcnt(0)" ::: "memory");

    // O^T += V^T P : vf (from Vsm) feeds 2 MFMA; P 2nd-operand via b64 pairs
#pragma unroll
    for (int kk = 0; kk < 4; ++kk) {   // 32-key chunks
      bf16x8 pf[2];
#pragma unroll
      for (int nq = 0; nq < 2; ++nq) {
        int row0 = kk * 8 + quad * 2;
        ushort4 lo = *(const ushort4*)&Plds[wave][((row0    ) * 32 + nq * 16 + lq) * 4];
        ushort4 hi = *(const ushort4*)&Plds[wave][((row0 + 1) * 32 + nq * 16 + lq) * 4];
        union { ushort4 u[2]; bf16x8 v; } cvt;
        cvt.u[0] = lo; cvt.u[1] = hi;
        pf[nq] = cvt.v;
      }
#pragma unroll
      for (int md = 0; md < 4; ++md) {
        int row = md * 16 + lq;
        int sw  = ((kk * 4 + quad) ^ (row & 15)) << 4;
        bf16x8 vf = *(const bf16x8*)((const char*)Vsm + row * 256 + sw);
        o_acc[md][0] = __builtin_amdgcn_mfma_f32_16x16x32_bf16(vf, pf[0], o_acc[md][0], 0, 0, 0);
        o_acc[md][1] = __builtin_amdgcn_mfma_f32_16x16x32_bf16(vf, pf[1], o_acc[md][1], 0, 0, 0);
      }
    }
    __syncthreads();
  }

  // epilogue: reduce l over the 4 quads (keys), normalize, packed ushort4 stores
  float inv[2];
#pragma unroll
  for (int nq = 0; nq < 2; ++nq) {
    float lsum = l_part[nq];
    lsum += __shfl_xor(lsum, 16);
    lsum += __shfl_xor(lsum, 32);
    inv[nq] = (lsum > 0.f) ? 1.f / lsum : 0.f;
  }
#pragma unroll
  for (int md = 0; md < 4; ++md) {
#pragma unroll
    for (int nq = 0; nq < 2; ++nq) {
      int t = qbase + nq * 16 + lq;
      int chan0 = h * HD + md * 16 + quad * 4;
      *(ushort4*)&O[((size_t)(b * T + t)) * K_DIM + chan0] =
          pk4(o_acc[md][nq][0] * inv[nq], o_acc[md][nq][1] * inv[nq],
              o_acc[md][nq][2] * inv[nq], o_acc[md][nq][3] * inv[nq]);
    }
  }
}

// ---------------- launch ----------------
extern "C" void kernel_launch(void* const* d_in, const int* in_sizes, int n_in,
                              void* d_out, int out_size, void* d_ws, size_t ws_size,
                              hipStream_t stream)
{
  const float* x       = (const float*)d_in[0];
  const int*   padding = (const int*)d_in[1];
  const float* Wq      = (const float*)d_in[2];
  const float* Wk      = (const float*)d_in[3];
  const float* Wv      = (const float*)d_in[4];
  const float* Wo      = (const float*)d_in[5];
  const float* bo      = (const float*)d_in[6];
  float* out = (float*)d_out;

  char* ws = (char*)d_ws;
  unsigned short* xb   = (unsigned short*)(ws);                 // 8 MB  x bf16 [4096][1024]
  unsigned short* wqkv = (unsigned short*)(ws + (8u  << 20));   // 6 MB  [Wq;Wk;Wv] bf16
  unsigned short* wob  = (unsigned short*)(ws + (14u << 20));   // 2 MB  Wo bf16
  unsigned short* qb   = (unsigned short*)(ws + (16u << 20));   // 8 MB  q [bh][t][d] (pre-scaled)
  unsigned short* kb   = (unsigned short*)(ws + (24u << 20));   // 8 MB  k [bh][t][d]
  unsigned short* vtb  = (unsigned short*)(ws + (32u << 20));   // 8 MB  v^T [bh][d][t]
  unsigned short* ab   = (unsigned short*)(ws + (40u << 20));   // 8 MB  attn-out [b*t][1024]

  convert_kernel<<<8192, 256, 0, stream>>>(x, Wq, Wk, Wv, Wo, xb, wqkv, wob);

  // fused Q,K,V projections: C[3072 chans][4096 tokens] = [Wq;Wk;Wv] @ x^T
  // 192x128 tile: grid (16,32) = 512 blocks = 2/CU, 40KB LDS
  gemm_bt<1, 192, 128><<<dim3(16, 32), 256, 0, stream>>>(wqkv, xb, qb, kb, vtb, nullptr, nullptr);

  // attention
  attn_kernel<<<dim3(32, 16), 256, 0, stream>>>(qb, kb, vtb, padding, ab);

  // output projection: C[1024 chans][4096 tokens] = Wo @ attn^T -> out[t][chan]+bo
  gemm_bt<2, 64, 128><<<dim3(16, 32), 256, 0, stream>>>(wob, ab, nullptr, nullptr, nullptr, out, bo);
}

// Round 11
// 184.970 us; speedup vs baseline: 1.0743x; 1.0098x over previous
//
#include <hip/hip_runtime.h>
#include <hip/hip_bf16.h>
#include <cmath>
#include <stdint.h>

// ---------------- problem constants ----------------
#define K_DIM 1024
#define NH    16
#define HD    64
#define T     2048
#define NTOK  4096   // b*t = 2*2048
#define NBH   32     // b*h

typedef __bf16 bf16x8 __attribute__((ext_vector_type(8)));
typedef float  f32x4  __attribute__((ext_vector_type(4)));

__device__ __forceinline__ unsigned short f2bf(float f) {
  union { float f; unsigned u; } v; v.f = f;
  unsigned u = v.u;
  return (unsigned short)((u + 0x7FFFu + ((u >> 16) & 1u)) >> 16);
}
// packed round-nearest-even via v_cvt_pk_bf16_f32
__device__ __forceinline__ ushort4 pk4(float a, float b, float c, float d) {
  union { __hip_bfloat162 h[2]; ushort4 u; } r;
  r.h[0] = __float22bfloat162_rn(float2{a, b});
  r.h[1] = __float22bfloat162_rn(float2{c, d});
  return r.u;
}

__device__ __forceinline__ void gload16(const void* g, void* l) {
  __builtin_amdgcn_global_load_lds(
      (__attribute__((address_space(1))) void*)(g),
      (__attribute__((address_space(3))) void*)(l),
      16, 0, 0);
}

// ---------------- fp32 -> bf16 conversion ----------------
// Wq is pre-scaled by 0.125*log2(e) so attn can exp2() scores directly.
__global__ void convert_kernel(const float* __restrict__ x,
                               const float* __restrict__ Wq,
                               const float* __restrict__ Wk,
                               const float* __restrict__ Wv,
                               const float* __restrict__ Wo,
                               unsigned short* __restrict__ xb,
                               unsigned short* __restrict__ wqkv,
                               unsigned short* __restrict__ wob)
{
  const size_t NX = (size_t)NTOK * K_DIM;   // 4M
  const size_t NW = (size_t)K_DIM * K_DIM;  // 1M
  size_t i = ((size_t)blockIdx.x * blockDim.x + threadIdx.x) * 4;
  const float* src; unsigned short* dst; size_t off;
  float scale = 1.f;
  if (i < NX)             { src = x;  dst = xb;          off = i; }
  else if (i < NX + NW)   { src = Wq; dst = wqkv;        off = i - NX;
                            scale = 0.18033688011112042f; }
  else if (i < NX + 2*NW) { src = Wk; dst = wqkv + NW;   off = i - NX - NW; }
  else if (i < NX + 3*NW) { src = Wv; dst = wqkv + 2*NW; off = i - NX - 2*NW; }
  else                    { src = Wo; dst = wob;         off = i - NX - 3*NW; }
  float4 v = *(const float4*)(src + off);
  *(ushort4*)(dst + off) = pk4(v.x * scale, v.y * scale, v.z * scale, v.w * scale);
}

// ---------------- B^T GEMM: C[m][n] = sum_k A[m*1024+k] * B[n*1024+k] ----------------
// TMxTN tile, BK=64, 256 threads (2x2 waves). XOR-swizzled LDS (chunk ^= row&7).
// MODE 1 (fused QKV): A=[Wq;Wk;Wv], m=chan in [0,3072), n=token; TM=192 for
//   balanced LDS:MFMA (10 b128 reads per 24 MFMA per kk-step).
//   q/k: packed ushort4 along d; v: b16 scatter to vt[bh][d][t] (t-coalesced).
// MODE 2 (out-proj):  A=Wo, m=chan in [0,1024), n=token -> out[t][chan]+bias, float4.
template <int MODE, int TM, int TN>
__global__ __launch_bounds__(256, 2)
void gemm_bt(const unsigned short* __restrict__ A,
             const unsigned short* __restrict__ B,
             unsigned short* __restrict__ o_q,
             unsigned short* __restrict__ o_k,
             unsigned short* __restrict__ o_v,
             float* __restrict__ o_f,
             const float* __restrict__ bias)
{
  __shared__ unsigned short Asm[TM * 64];
  __shared__ unsigned short Bsm[TN * 64];
  const int tid  = threadIdx.x;
  const int wave = tid >> 6;
  const int lane = tid & 63;
  const int lq   = lane & 15;
  const int quad = lane >> 4;
  const int bm = blockIdx.x, bn = blockIdx.y;
  const int wm = (wave >> 1) * (TM / 2), wn = (wave & 1) * (TN / 2);
  const int MT = TM / 32, NT = TN / 32;

  f32x4 acc[MT][NT];
#pragma unroll
  for (int i = 0; i < MT; ++i)
#pragma unroll
    for (int j = 0; j < NT; ++j) acc[i][j] = (f32x4){0.f, 0.f, 0.f, 0.f};

  const char* Ab = (const char*)(A + (size_t)bm * TM * K_DIM);
  const char* Bb = (const char*)(B + (size_t)bn * TN * K_DIM);

  for (int k0 = 0; k0 < K_DIM; k0 += 64) {
#pragma unroll
    for (int i = 0; i < MT; ++i) {
      int off   = i * 4096 + wave * 1024 + lane * 16;
      int row   = off >> 7;
      int chunk = (off >> 4) & 7;
      int scol  = (chunk ^ (row & 7)) << 4;
      gload16(Ab + (size_t)row * (K_DIM * 2) + (size_t)k0 * 2 + scol,
              (char*)Asm + off - lane * 16);
    }
#pragma unroll
    for (int i = 0; i < NT; ++i) {
      int off   = i * 4096 + wave * 1024 + lane * 16;
      int row   = off >> 7;
      int chunk = (off >> 4) & 7;
      int scol  = (chunk ^ (row & 7)) << 4;
      gload16(Bb + (size_t)row * (K_DIM * 2) + (size_t)k0 * 2 + scol,
              (char*)Bsm + off - lane * 16);
    }
    __syncthreads();
#pragma unroll
    for (int kk = 0; kk < 64; kk += 32) {
      bf16x8 af[MT], bfr[NT];
#pragma unroll
      for (int mt = 0; mt < MT; ++mt) {
        int row = wm + mt * 16 + lq;
        int sw  = (quad + (kk >> 3)) ^ (row & 7);
        af[mt] = *(const bf16x8*)((const char*)Asm + row * 128 + (sw << 4));
      }
#pragma unroll
      for (int nt = 0; nt < NT; ++nt) {
        int row = wn + nt * 16 + lq;
        int sw  = (quad + (kk >> 3)) ^ (row & 7);
        bfr[nt] = *(const bf16x8*)((const char*)Bsm + row * 128 + (sw << 4));
      }
#pragma unroll
      for (int mt = 0; mt < MT; ++mt)
#pragma unroll
        for (int nt = 0; nt < NT; ++nt)
          acc[mt][nt] = __builtin_amdgcn_mfma_f32_16x16x32_bf16(af[mt], bfr[nt], acc[mt][nt], 0, 0, 0);
    }
    __syncthreads();
  }

  // epilogues: acc r=0..3 are 4 consecutive m (chans)
#pragma unroll
  for (int mt = 0; mt < MT; ++mt) {
    int mbase = bm * TM + wm + mt * 16 + quad * 4;
#pragma unroll
    for (int nt = 0; nt < NT; ++nt) {
      int n = bn * TN + wn + nt * 16 + lq;
      if (MODE == 1) {
        int which = mbase >> 10, c = mbase & 1023;   // uniform per 16-row tile
        int h = c >> 6, d0 = c & 63;
        int b = n >> 11, t = n & 2047;
        if (which < 2) {
          ushort4 pk = pk4(acc[mt][nt][0], acc[mt][nt][1], acc[mt][nt][2], acc[mt][nt][3]);
          unsigned short* dst = which ? o_k : o_q;
          *(ushort4*)&dst[((size_t)(b * NH + h) * T + t) * HD + d0] = pk;
        } else {
          // vt[bh][d][t]: consecutive lanes -> consecutive t (coalesced segments)
#pragma unroll
          for (int r = 0; r < 4; ++r)
            o_v[((size_t)(b * NH + h) * HD + d0 + r) * T + t] = f2bf(acc[mt][nt][r]);
        }
      } else {
        float4 bv = *(const float4*)&bias[mbase];
        float4 o;
        o.x = acc[mt][nt][0] + bv.x; o.y = acc[mt][nt][1] + bv.y;
        o.z = acc[mt][nt][2] + bv.z; o.w = acc[mt][nt][3] + bv.w;
        *(float4*)&o_f[(size_t)n * K_DIM + mbase] = o;
      }
    }
  }
}

// ---------------- flash attention (S^T / O^T, software-pipelined staging) ----------------
// grid (32 bh, 16 q-tiles): XCD = linear%8 tracks bh -> L2 locality (FETCH ~12MB).
// S^T = K Q^T -> lane's 4 C-regs = 4 consecutive keys -> P^T packs as b64 write.
// O^T = V^T P, full-width 128-key PV. Pipeline: QK(kt) -> syncA (cheap, no vmcnt)
// -> issue stage K(kt+1)/V(kt+1) -> exp2+Pwrite+PV (covers the DMA) -> syncB
// (drain mostly complete). V double-buffered (K single: re-staged only after
// syncA proves all waves consumed it). 80KB LDS -> 2 blocks/CU.
__global__ __launch_bounds__(256, 2)
void attn_kernel(const unsigned short* __restrict__ Q,
                 const unsigned short* __restrict__ Kb,
                 const unsigned short* __restrict__ Vt,
                 const int* __restrict__ padding,
                 unsigned short* __restrict__ O)
{
  __shared__ unsigned short Ksm[128 * 64];        // 16 KB [key][d], 128B rows, swiz &7
  __shared__ unsigned short Vsm[2][64 * 128];     // 2x16 KB [d][key], 256B rows, swiz &15
  __shared__ unsigned short Plds[4][32 * 32 * 4]; // 32 KB: per wave P^T[key/4][q] ushort4

  const int tid  = threadIdx.x;
  const int wave = tid >> 6;
  const int lane = tid & 63;
  const int lq   = lane & 15;
  const int quad = lane >> 4;
  const int bh = blockIdx.x;
  const int qt = blockIdx.y;
  const int b  = bh >> 4;
  const int h  = bh & 15;
  const int qbase = qt * 128 + wave * 32;

  // Q fragments (2nd operand): lane holds q = qbase+nq*16+lq, k = kk*32+quad*8+j
  bf16x8 qf[2][2];
#pragma unroll
  for (int nq = 0; nq < 2; ++nq)
#pragma unroll
    for (int kk = 0; kk < 2; ++kk)
      qf[nq][kk] = *(const bf16x8*)&Q[((size_t)bh * T + qbase + nq * 16 + lq) * HD + kk * 32 + quad * 8];

  f32x4 o_acc[4][2];   // [d-tile][q-tile]; O^T[d][q]
#pragma unroll
  for (int md = 0; md < 4; ++md)
#pragma unroll
    for (int nq = 0; nq < 2; ++nq) o_acc[md][nq] = (f32x4){0.f, 0.f, 0.f, 0.f};
  float l_part[2] = {0.f, 0.f};

  // stage tile kt into Ksm and Vsm[buf]
  auto stage = [&](int kt, int buf) {
#pragma unroll
    for (int i = 0; i < 4; ++i) {
      int off = i * 4096 + wave * 1024 + lane * 16;
      {  // K: 128B rows
        int row = off >> 7, chunk = (off >> 4) & 7;
        int scol = (chunk ^ (row & 7)) << 4;
        gload16((const char*)Kb + ((size_t)(bh * T + kt * 128 + row) * HD) * 2 + scol,
                (char*)Ksm + off - lane * 16);
      }
      {  // Vt: 256B rows
        int row = off >> 8, chunk = (off >> 4) & 15;
        int scol = (chunk ^ (row & 15)) << 4;
        gload16((const char*)Vt + ((size_t)(bh * HD + row) * T + (size_t)kt * 128) * 2 + scol,
                (char*)Vsm[buf] + off - lane * 16);
      }
    }
  };

  stage(0, 0);
  __syncthreads();

  for (int kt = 0; kt < T / 128; ++kt) {
    const int cur = kt & 1;

    // S^T = K Q^T : 128 keys x 32 q per wave; kf (from Ksm) feeds 2 MFMA
    f32x4 st[8][2];
#pragma unroll
    for (int nt = 0; nt < 8; ++nt)
#pragma unroll
      for (int nq = 0; nq < 2; ++nq) st[nt][nq] = (f32x4){0.f, 0.f, 0.f, 0.f};
#pragma unroll
    for (int kk = 0; kk < 2; ++kk) {
#pragma unroll
      for (int nt = 0; nt < 8; ++nt) {
        int row = nt * 16 + lq;
        int sw  = (quad + kk * 4) ^ (row & 7);
        bf16x8 kf = *(const bf16x8*)((const char*)Ksm + row * 128 + (sw << 4));
        st[nt][0] = __builtin_amdgcn_mfma_f32_16x16x32_bf16(kf, qf[0][kk], st[nt][0], 0, 0, 0);
        st[nt][1] = __builtin_amdgcn_mfma_f32_16x16x32_bf16(kf, qf[1][kk], st[nt][1], 0, 0, 0);
      }
    }

    // all waves have consumed Ksm (cheap barrier: no vmcnt pending)
    __syncthreads();

    // prefetch next tile: DMA overlaps exp2 + P write + PV below
    if (kt < T / 128 - 1) stage(kt + 1, cur ^ 1);

    // exp2 + padding mask + partial row sums; pack 4 consecutive keys -> b64 write
#pragma unroll
    for (int nt = 0; nt < 8; ++nt) {
      int4 pd = *(const int4*)&padding[b * T + kt * 128 + nt * 16 + quad * 4];
#pragma unroll
      for (int nq = 0; nq < 2; ++nq) {
        float p0 = pd.x ? __builtin_amdgcn_exp2f(st[nt][nq][0]) : 0.f;
        float p1 = pd.y ? __builtin_amdgcn_exp2f(st[nt][nq][1]) : 0.f;
        float p2 = pd.z ? __builtin_amdgcn_exp2f(st[nt][nq][2]) : 0.f;
        float p3 = pd.w ? __builtin_amdgcn_exp2f(st[nt][nq][3]) : 0.f;
        l_part[nq] += (p0 + p1) + (p2 + p3);
        int row = nt * 4 + quad;          // key/4
        int col = nq * 16 + lq;           // q
        *(ushort4*)&Plds[wave][(row * 32 + col) * 4] = pk4(p0, p1, p2, p3);
      }
    }
    asm volatile("s_waitcnt lgkmcnt(0)" ::: "memory");

    // O^T += V^T P : vf (from Vsm[cur]) feeds 2 MFMA; P 2nd-operand via b64 pairs
#pragma unroll
    for (int kk = 0; kk < 4; ++kk) {   // 32-key chunks
      bf16x8 pf[2];
#pragma unroll
      for (int nq = 0; nq < 2; ++nq) {
        int row0 = kk * 8 + quad * 2;
        ushort4 lo = *(const ushort4*)&Plds[wave][((row0    ) * 32 + nq * 16 + lq) * 4];
        ushort4 hi = *(const ushort4*)&Plds[wave][((row0 + 1) * 32 + nq * 16 + lq) * 4];
        union { ushort4 u[2]; bf16x8 v; } cvt;
        cvt.u[0] = lo; cvt.u[1] = hi;
        pf[nq] = cvt.v;
      }
#pragma unroll
      for (int md = 0; md < 4; ++md) {
        int row = md * 16 + lq;
        int sw  = ((kk * 4 + quad) ^ (row & 15)) << 4;
        bf16x8 vf = *(const bf16x8*)((const char*)Vsm[cur] + row * 256 + sw);
        o_acc[md][0] = __builtin_amdgcn_mfma_f32_16x16x32_bf16(vf, pf[0], o_acc[md][0], 0, 0, 0);
        o_acc[md][1] = __builtin_amdgcn_mfma_f32_16x16x32_bf16(vf, pf[1], o_acc[md][1], 0, 0, 0);
      }
    }

    // staging drain: mostly complete (exp2+Pwrite+PV covered the DMA)
    __syncthreads();
  }

  // epilogue: reduce l over the 4 quads (keys), normalize, packed ushort4 stores
  float inv[2];
#pragma unroll
  for (int nq = 0; nq < 2; ++nq) {
    float lsum = l_part[nq];
    lsum += __shfl_xor(lsum, 16);
    lsum += __shfl_xor(lsum, 32);
    inv[nq] = (lsum > 0.f) ? 1.f / lsum : 0.f;
  }
#pragma unroll
  for (int md = 0; md < 4; ++md) {
#pragma unroll
    for (int nq = 0; nq < 2; ++nq) {
      int t = qbase + nq * 16 + lq;
      int chan0 = h * HD + md * 16 + quad * 4;
      *(ushort4*)&O[((size_t)(b * T + t)) * K_DIM + chan0] =
          pk4(o_acc[md][nq][0] * inv[nq], o_acc[md][nq][1] * inv[nq],
              o_acc[md][nq][2] * inv[nq], o_acc[md][nq][3] * inv[nq]);
    }
  }
}

// ---------------- launch ----------------
extern "C" void kernel_launch(void* const* d_in, const int* in_sizes, int n_in,
                              void* d_out, int out_size, void* d_ws, size_t ws_size,
                              hipStream_t stream)
{
  const float* x       = (const float*)d_in[0];
  const int*   padding = (const int*)d_in[1];
  const float* Wq      = (const float*)d_in[2];
  const float* Wk      = (const float*)d_in[3];
  const float* Wv      = (const float*)d_in[4];
  const float* Wo      = (const float*)d_in[5];
  const float* bo      = (const float*)d_in[6];
  float* out = (float*)d_out;

  char* ws = (char*)d_ws;
  unsigned short* xb   = (unsigned short*)(ws);                 // 8 MB  x bf16 [4096][1024]
  unsigned short* wqkv = (unsigned short*)(ws + (8u  << 20));   // 6 MB  [Wq;Wk;Wv] bf16
  unsigned short* wob  = (unsigned short*)(ws + (14u << 20));   // 2 MB  Wo bf16
  unsigned short* qb   = (unsigned short*)(ws + (16u << 20));   // 8 MB  q [bh][t][d] (pre-scaled)
  unsigned short* kb   = (unsigned short*)(ws + (24u << 20));   // 8 MB  k [bh][t][d]
  unsigned short* vtb  = (unsigned short*)(ws + (32u << 20));   // 8 MB  v^T [bh][d][t]
  unsigned short* ab   = (unsigned short*)(ws + (40u << 20));   // 8 MB  attn-out [b*t][1024]

  convert_kernel<<<8192, 256, 0, stream>>>(x, Wq, Wk, Wv, Wo, xb, wqkv, wob);

  // fused Q,K,V projections: C[3072 chans][4096 tokens] = [Wq;Wk;Wv] @ x^T
  gemm_bt<1, 192, 128><<<dim3(16, 32), 256, 0, stream>>>(wqkv, xb, qb, kb, vtb, nullptr, nullptr);

  // attention
  attn_kernel<<<dim3(32, 16), 256, 0, stream>>>(qb, kb, vtb, padding, ab);

  // output projection: C[1024 chans][4096 tokens] = Wo @ attn^T -> out[t][chan]+bo
  gemm_bt<2, 64, 128><<<dim3(16, 32), 256, 0, stream>>>(wob, ab, nullptr, nullptr, nullptr, out, bo);
}